// Round 7
// baseline (7599.951 us; speedup 1.0000x reference)
//
#include <hip/hip_runtime.h>
#include <math.h>

// ---------------------------------------------------------------------------
// RGN round 12: R10 (best, bulk respin) with 50 fatter blocks/dir.
//   Theory: per-step period = chain latency + E[max-of-N block jitter]; N and
//   LLC line fan-out both halve with 16-unit blocks. Per wave: same B-tile
//   loads, 4 M-tiles (2x arithmetic intensity). Canary (R11, regression)
//   reverted.
//   - h layout hp[t][KT][q][b][8] (fragment order, coalesced tile reads).
//   - h1/h2 sentinel 0xFFFF (f16 NaN, impossible LSTM output), relaxed
//     agent-scope u64 loads/stores at LLC, no fences, no flags, no barrier.
//   - bulk prefetch at top of step; bulk respin re-reads all dirty tiles per
//     round (overlapped RTTs); pa/px cross-step register prefetch for phase A.
//   - A-rows gate-major over 64 rows: row = gate*16 + unit_lo (gate = mt).
// ---------------------------------------------------------------------------

#define TT 512
#define BB 32
#define HH 800
#define DIN 41
#define KROW 1600

typedef _Float16 f16;
typedef _Float16 half8 __attribute__((ext_vector_type(8)));
typedef float floatx4 __attribute__((ext_vector_type(4)));
typedef unsigned uint4v __attribute__((ext_vector_type(4)));

// ---------------- workspace layout (float-slot offsets) --------------------
// hp layout: [t][KT][q][b][8] f16; per t: 50*4*32*8 = 51200 f16 (=1600*32)
#define OFF_XT   8192                       // xp f16 [512][2][4][32][8]
#define OFF_H1   (OFF_XT + 524288)          // hp1 f16 [512][50][4][32][8]
#define OFF_H2   (OFF_H1 + 13107200)        // hp2 f16 [512][50][4][32][8]
#define OFF_ANG  (OFF_H2 + 13107200)        // f32 [512][32][3]
#define OFF_SIN  (OFF_ANG + 49152)
#define OFF_COS  (OFF_SIN + 64)

#define SENT 0xFFFFFFFFFFFFFFFFull

__device__ __forceinline__ float sigm(float x) { return 1.0f / (1.0f + expf(-x)); }

union U64H8 { unsigned long long u[2]; half8 h; };

__device__ __forceinline__ unsigned long long ald8(const f16* p) {
    return __hip_atomic_load((const unsigned long long*)p, __ATOMIC_RELAXED, __HIP_MEMORY_SCOPE_AGENT);
}
__device__ __forceinline__ void ast8(f16* p, unsigned long long v) {
    __hip_atomic_store((unsigned long long*)p, v, __ATOMIC_RELAXED, __HIP_MEMORY_SCOPE_AGENT);
}
__device__ __forceinline__ half8 cvt8(const float* p) {
    half8 r;
#pragma unroll
    for (int i = 0; i < 8; ++i) r[i] = (f16)p[i];
    return r;
}

// fragment-order index (in f16 units): hp[t][KT][q][b][0]
__device__ __forceinline__ size_t hpi(int t, int KT, int q, int b) {
    return ((((size_t)t * 50 + KT) * 4 + q) * 32 + b) * 8;
}

// ===========================================================================
// rnn0: layer 0. 50 blocks/dir, 16 units/block, 8 waves, K-split 8.
// kt = w + 8*i (i<4). kt<2: x (cached, packed); 2<=kt<27: h1 prev (bypass).
// A rows: 64 = gate(mt)*16 + l15(unit offset).
// ===========================================================================
__global__ __launch_bounds__(512, 1) void rnn0_kernel(
    const f16* __restrict__ xp, f16* __restrict__ h1,
    const float* __restrict__ Wih_f0, const float* __restrict__ Whh_f0, const float* __restrict__ b_f0,
    const float* __restrict__ Wih_b0, const float* __restrict__ Whh_b0, const float* __restrict__ b_b0)
{
    __shared__ float gbuf[8][64][34];
    __shared__ f16  hbuf[512];

    const int tid  = threadIdx.x;
    const int w    = tid >> 6;          // 0..7
    const int lane = tid & 63;
    const int l15  = lane & 15;
    const int quad = lane >> 4;
    const int dir  = blockIdx.x / 50;
    const int blk  = blockIdx.x % 50;
    const int j0   = blk * 16;
    const int jl   = tid >> 5;          // epilogue: hidden unit 0..15
    const int bb   = tid & 31;          // epilogue: batch

    const float* Wih = dir ? Wih_b0 : Wih_f0;
    const float* Whh = dir ? Whh_b0 : Whh_f0;
    const float* bs  = dir ? b_b0  : b_f0;

    // A-fragments: row = mt*16 + l15 -> gate mt, unit j0+l15
    half8 afr[4][4];
#pragma unroll
    for (int mt = 0; mt < 4; ++mt) {
        const int grow = mt * HH + j0 + l15;
#pragma unroll
        for (int i = 0; i < 4; ++i) {
            const int kt = w + 8 * i;
            half8 v;
#pragma unroll
            for (int jj = 0; jj < 8; ++jj) v[jj] = (f16)0.f;
            if (kt < 27) {
                if (kt < 2) {
#pragma unroll
                    for (int jj = 0; jj < 8; ++jj) {
                        const int k = kt * 32 + quad * 8 + jj;
                        if (k < DIN) v[jj] = (f16)Wih[(size_t)grow * DIN + k];
                    }
                } else {
                    v = cvt8(Whh + (size_t)grow * HH + (kt - 2) * 32 + quad * 8);
                }
            }
            afr[mt][i] = v;
        }
    }
    const float bi = bs[0 * HH + j0 + jl], bf = bs[1 * HH + j0 + jl],
                bg = bs[2 * HH + j0 + jl], bo = bs[3 * HH + j0 + jl];

    // producer store coords: 8-unit groups g8 = blk*2 + g (g=0,1)
    // store thread: tid<64 -> b = tid&31, g = tid>>5
    const int g8   = blk * 2 + (tid >> 5);      // valid when tid < 64
    const int sKT  = dir * 25 + (g8 >> 2);
    const int sq   = g8 & 3;

    // phase-A prefetch registers (x tile, waves 0,1 only)
    half8 px0, px1;
    {
        const int t0 = dir ? (TT - 1) : 0;
        if (w < 2) {
            const f16* p = xp + ((((size_t)t0 * 2 + w) * 4 + quad) * 32) * 8;
            px0 = *(const half8*)(p + (size_t)l15 * 8);
            px1 = *(const half8*)(p + (size_t)(16 + l15) * 8);
        }
    }

    float creg = 0.0f;
    for (int s = 0; s < TT; ++s) {
        const int t  = dir ? (TT - 1 - s) : s;
        const int tp = dir ? t + 1 : t - 1;
        const int tn = dir ? (t > 0 ? t - 1 : 0) : (t < TT - 1 ? t + 1 : t);

        // ---- (1) early bulk prefetch of bypass tiles ----
        U64H8 rb[4][2];
        if (s > 0) {
#pragma unroll
            for (int i = 0; i < 4; ++i) {
                const int kt = w + 8 * i;
                if (kt >= 2 && kt < 27) {
                    const f16* p = h1 + hpi(tp, dir * 25 + (kt - 2), quad, 0);
                    rb[i][0].u[0] = ald8(p + (size_t)l15 * 8);
                    rb[i][0].u[1] = ald8(p + (size_t)l15 * 8 + 4);
                    rb[i][1].u[0] = ald8(p + (size_t)(16 + l15) * 8);
                    rb[i][1].u[1] = ald8(p + (size_t)(16 + l15) * 8 + 4);
                }
            }
        }

        floatx4 acc[4][2];
#pragma unroll
        for (int mt = 0; mt < 4; ++mt) { acc[mt][0] = (floatx4)0.f; acc[mt][1] = (floatx4)0.f; }

        // ---- (2) phase A: x tile MFMA from prefetched regs (waves 0,1) ----
        if (w < 2) {
#pragma unroll
            for (int mt = 0; mt < 4; ++mt) {
                acc[mt][0] = __builtin_amdgcn_mfma_f32_16x16x32_f16(afr[mt][0], px0, acc[mt][0], 0, 0, 0);
                acc[mt][1] = __builtin_amdgcn_mfma_f32_16x16x32_f16(afr[mt][0], px1, acc[mt][1], 0, 0, 0);
            }
            // reload px for next step (completes under phase-B wait)
            const f16* p = xp + ((((size_t)tn * 2 + w) * 4 + quad) * 32) * 8;
            px0 = *(const half8*)(p + (size_t)l15 * 8);
            px1 = *(const half8*)(p + (size_t)(16 + l15) * 8);
        }

        // ---- (3) phase B: bulk verify + bulk respin ----
        if (s > 0) {
            int dm = 0;
#pragma unroll
            for (int i = 0; i < 4; ++i) {
                const int kt = w + 8 * i;
                if (kt >= 2 && kt < 27) {
                    const int bad = (rb[i][0].u[0] == SENT) | (rb[i][0].u[1] == SENT) |
                                    (rb[i][1].u[0] == SENT) | (rb[i][1].u[1] == SENT);
                    dm |= bad << i;
                }
            }
            while (__any(dm != 0)) {
#pragma unroll
                for (int i = 0; i < 4; ++i) {
                    const int kt = w + 8 * i;
                    if (kt >= 2 && kt < 27) {
                        if (dm & (1 << i)) {
                            const f16* p = h1 + hpi(tp, dir * 25 + (kt - 2), quad, 0);
                            rb[i][0].u[0] = ald8(p + (size_t)l15 * 8);
                            rb[i][0].u[1] = ald8(p + (size_t)l15 * 8 + 4);
                            rb[i][1].u[0] = ald8(p + (size_t)(16 + l15) * 8);
                            rb[i][1].u[1] = ald8(p + (size_t)(16 + l15) * 8 + 4);
                        }
                    }
                }
                int nm = 0;
#pragma unroll
                for (int i = 0; i < 4; ++i) {
                    const int kt = w + 8 * i;
                    if (kt >= 2 && kt < 27) {
                        if (dm & (1 << i)) {
                            const int bad = (rb[i][0].u[0] == SENT) | (rb[i][0].u[1] == SENT) |
                                            (rb[i][1].u[0] == SENT) | (rb[i][1].u[1] == SENT);
                            nm |= bad << i;
                        }
                    }
                }
                dm = nm;
            }
            // ---- phase B MFMA ----
#pragma unroll
            for (int i = 0; i < 4; ++i) {
                const int kt = w + 8 * i;
                if (kt >= 2 && kt < 27) {
#pragma unroll
                    for (int mt = 0; mt < 4; ++mt) {
                        acc[mt][0] = __builtin_amdgcn_mfma_f32_16x16x32_f16(afr[mt][i], rb[i][0].h, acc[mt][0], 0, 0, 0);
                        acc[mt][1] = __builtin_amdgcn_mfma_f32_16x16x32_f16(afr[mt][i], rb[i][1].h, acc[mt][1], 0, 0, 0);
                    }
                }
            }
        }

        // ---- (4) cross-wave reduce + epilogue ----
#pragma unroll
        for (int mt = 0; mt < 4; ++mt)
#pragma unroll
            for (int nt = 0; nt < 2; ++nt)
#pragma unroll
                for (int rg = 0; rg < 4; ++rg)
                    gbuf[w][mt * 16 + quad * 4 + rg][nt * 16 + l15] = acc[mt][nt][rg];
        __syncthreads();
        {
            float gi_ = bi, gf_ = bf, gc_ = bg, go_ = bo;
#pragma unroll
            for (int ww = 0; ww < 8; ++ww) {
                gi_ += gbuf[ww][jl][bb];
                gf_ += gbuf[ww][16 + jl][bb];
                gc_ += gbuf[ww][32 + jl][bb];
                go_ += gbuf[ww][48 + jl][bb];
            }
            const float cn = sigm(gf_) * creg + sigm(gi_) * tanhf(gc_);
            creg = cn;
            hbuf[bb * 16 + jl] = (f16)(sigm(go_) * tanhf(cn));
        }
        __syncthreads();
        if (tid < 64) {
            const int b = tid & 31;
            f16* dst = h1 + hpi(t, sKT, sq, b);
            const unsigned long long* src = (const unsigned long long*)(hbuf + b * 16 + (tid >> 5) * 8);
            ast8(dst, src[0]);
            ast8(dst + 4, src[1]);
        }
    }
}

// ===========================================================================
// rnn1: layer 1. 50 blocks/dir, 16 units/block, 8 waves, K-split 8.
// kt = w + 8*i. kt<50: h1[t] (cached); 50<=kt<75 (i in 6..9): h2 prev.
// ===========================================================================
__global__ __launch_bounds__(512, 1) void rnn1_kernel(
    const f16* __restrict__ h1, f16* __restrict__ h2,
    const float* __restrict__ Wih_f1, const float* __restrict__ Whh_f1, const float* __restrict__ b_f1,
    const float* __restrict__ Wih_b1, const float* __restrict__ Whh_b1, const float* __restrict__ b_b1)
{
    __shared__ float gbuf[8][64][34];
    __shared__ f16  hbuf[512];

    const int tid  = threadIdx.x;
    const int w    = tid >> 6;
    const int lane = tid & 63;
    const int l15  = lane & 15;
    const int quad = lane >> 4;
    const int dir  = blockIdx.x / 50;
    const int blk  = blockIdx.x % 50;
    const int j0   = blk * 16;
    const int jl   = tid >> 5;
    const int bb   = tid & 31;

    const float* Wih = dir ? Wih_b1 : Wih_f1;
    const float* Whh = dir ? Whh_b1 : Whh_f1;
    const float* bs  = dir ? b_b1  : b_f1;

    half8 afr[4][10];
#pragma unroll
    for (int mt = 0; mt < 4; ++mt) {
        const int grow = mt * HH + j0 + l15;
#pragma unroll
        for (int i = 0; i < 10; ++i) {
            const int kt = w + 8 * i;
            half8 v;
#pragma unroll
            for (int jj = 0; jj < 8; ++jj) v[jj] = (f16)0.f;
            if (kt < 75) {
                if (kt < 50) v = cvt8(Wih + (size_t)grow * KROW + kt * 32 + quad * 8);
                else         v = cvt8(Whh + (size_t)grow * HH + (kt - 50) * 32 + quad * 8);
            }
            afr[mt][i] = v;
        }
    }
    const float bi = bs[0 * HH + j0 + jl], bf = bs[1 * HH + j0 + jl],
                bg = bs[2 * HH + j0 + jl], bo = bs[3 * HH + j0 + jl];

    const int g8   = blk * 2 + (tid >> 5);      // valid when tid < 64
    const int sKT  = dir * 25 + (g8 >> 2);
    const int sq   = g8 & 3;

    // phase-A prefetch registers: up to 7 tiles (kt = w+8i < 50)
    half8 pa[7][2];
    {
        const int t0 = dir ? (TT - 1) : 0;
#pragma unroll
        for (int i = 0; i < 7; ++i) {
            const int kt = w + 8 * i;
            if (kt < 50) {
                const f16* p = h1 + hpi(t0, kt, quad, 0);
                pa[i][0] = *(const half8*)(p + (size_t)l15 * 8);
                pa[i][1] = *(const half8*)(p + (size_t)(16 + l15) * 8);
            }
        }
    }

    float creg = 0.0f;
    for (int s = 0; s < TT; ++s) {
        const int t  = dir ? (TT - 1 - s) : s;
        const int tp = dir ? t + 1 : t - 1;
        const int tn = dir ? (t > 0 ? t - 1 : 0) : (t < TT - 1 ? t + 1 : t);

        // ---- (1) early bulk prefetch of bypass tiles ----
        U64H8 rb[4][2];
        if (s > 0) {
#pragma unroll
            for (int i = 6; i < 10; ++i) {
                const int kt = w + 8 * i;
                if (kt >= 50 && kt < 75) {
                    const f16* p = h2 + hpi(tp, dir * 25 + (kt - 50), quad, 0);
                    rb[i - 6][0].u[0] = ald8(p + (size_t)l15 * 8);
                    rb[i - 6][0].u[1] = ald8(p + (size_t)l15 * 8 + 4);
                    rb[i - 6][1].u[0] = ald8(p + (size_t)(16 + l15) * 8);
                    rb[i - 6][1].u[1] = ald8(p + (size_t)(16 + l15) * 8 + 4);
                }
            }
        }

        floatx4 acc[4][2];
#pragma unroll
        for (int mt = 0; mt < 4; ++mt) { acc[mt][0] = (floatx4)0.f; acc[mt][1] = (floatx4)0.f; }

        // ---- (2) phase A: h1[t] MFMA from prefetched regs ----
#pragma unroll
        for (int i = 0; i < 7; ++i) {
            const int kt = w + 8 * i;
            if (kt < 50) {
#pragma unroll
                for (int mt = 0; mt < 4; ++mt) {
                    acc[mt][0] = __builtin_amdgcn_mfma_f32_16x16x32_f16(afr[mt][i], pa[i][0], acc[mt][0], 0, 0, 0);
                    acc[mt][1] = __builtin_amdgcn_mfma_f32_16x16x32_f16(afr[mt][i], pa[i][1], acc[mt][1], 0, 0, 0);
                }
            }
        }

        // ---- (3) reload pa for next step (completes under phase-B wait) ----
#pragma unroll
        for (int i = 0; i < 7; ++i) {
            const int kt = w + 8 * i;
            if (kt < 50) {
                const f16* p = h1 + hpi(tn, kt, quad, 0);
                pa[i][0] = *(const half8*)(p + (size_t)l15 * 8);
                pa[i][1] = *(const half8*)(p + (size_t)(16 + l15) * 8);
            }
        }

        // ---- (4) phase B: bulk verify + bulk respin ----
        if (s > 0) {
            int dm = 0;
#pragma unroll
            for (int i = 6; i < 10; ++i) {
                const int kt = w + 8 * i;
                if (kt >= 50 && kt < 75) {
                    const int bad = (rb[i - 6][0].u[0] == SENT) | (rb[i - 6][0].u[1] == SENT) |
                                    (rb[i - 6][1].u[0] == SENT) | (rb[i - 6][1].u[1] == SENT);
                    dm |= bad << (i - 6);
                }
            }
            while (__any(dm != 0)) {
#pragma unroll
                for (int i = 6; i < 10; ++i) {
                    const int kt = w + 8 * i;
                    if (kt >= 50 && kt < 75) {
                        if (dm & (1 << (i - 6))) {
                            const f16* p = h2 + hpi(tp, dir * 25 + (kt - 50), quad, 0);
                            rb[i - 6][0].u[0] = ald8(p + (size_t)l15 * 8);
                            rb[i - 6][0].u[1] = ald8(p + (size_t)l15 * 8 + 4);
                            rb[i - 6][1].u[0] = ald8(p + (size_t)(16 + l15) * 8);
                            rb[i - 6][1].u[1] = ald8(p + (size_t)(16 + l15) * 8 + 4);
                        }
                    }
                }
                int nm = 0;
#pragma unroll
                for (int i = 6; i < 10; ++i) {
                    const int kt = w + 8 * i;
                    if (kt >= 50 && kt < 75) {
                        if (dm & (1 << (i - 6))) {
                            const int bad = (rb[i - 6][0].u[0] == SENT) | (rb[i - 6][0].u[1] == SENT) |
                                            (rb[i - 6][1].u[0] == SENT) | (rb[i - 6][1].u[1] == SENT);
                            nm |= bad << (i - 6);
                        }
                    }
                }
                dm = nm;
            }
            // ---- phase B MFMA ----
#pragma unroll
            for (int i = 6; i < 10; ++i) {
                const int kt = w + 8 * i;
                if (kt >= 50 && kt < 75) {
#pragma unroll
                    for (int mt = 0; mt < 4; ++mt) {
                        acc[mt][0] = __builtin_amdgcn_mfma_f32_16x16x32_f16(afr[mt][i], rb[i - 6][0].h, acc[mt][0], 0, 0, 0);
                        acc[mt][1] = __builtin_amdgcn_mfma_f32_16x16x32_f16(afr[mt][i], rb[i - 6][1].h, acc[mt][1], 0, 0, 0);
                    }
                }
            }
        }

        // ---- (5) cross-wave reduce + epilogue ----
#pragma unroll
        for (int mt = 0; mt < 4; ++mt)
#pragma unroll
            for (int nt = 0; nt < 2; ++nt)
#pragma unroll
                for (int rg = 0; rg < 4; ++rg)
                    gbuf[w][mt * 16 + quad * 4 + rg][nt * 16 + l15] = acc[mt][nt][rg];
        __syncthreads();
        {
            float gi_ = bi, gf_ = bf, gc_ = bg, go_ = bo;
#pragma unroll
            for (int ww = 0; ww < 8; ++ww) {
                gi_ += gbuf[ww][jl][bb];
                gf_ += gbuf[ww][16 + jl][bb];
                gc_ += gbuf[ww][32 + jl][bb];
                go_ += gbuf[ww][48 + jl][bb];
            }
            const float cn = sigm(gf_) * creg + sigm(gi_) * tanhf(gc_);
            creg = cn;
            hbuf[bb * 16 + jl] = (f16)(sigm(go_) * tanhf(cn));
        }
        __syncthreads();
        if (tid < 64) {
            const int b = tid & 31;
            f16* dst = h2 + hpi(t, sKT, sq, b);
            const unsigned long long* src = (const unsigned long long*)(hbuf + b * 16 + (tid >> 5) * 8);
            ast8(dst, src[0]);
            ast8(dst + 4, src[1]);
        }
    }
}

// ---------------------------------------------------------------------------
// prep: xp packed f16, sin/cos tables, sentinel-fill h1+h2 (105 MB)
__global__ void prep_kernel(const float* __restrict__ x, const float* __restrict__ alphabet,
                            f16* __restrict__ xp, float* __restrict__ sin_t,
                            float* __restrict__ cos_t, unsigned* __restrict__ hsent) {
    const int gid = blockIdx.x * blockDim.x + threadIdx.x;
    const int nth = gridDim.x * blockDim.x;
    for (int idx = gid; idx < TT * BB * 64; idx += nth) {
        const int tb = idx >> 6;            // t*32+b
        const int i  = idx & 63;
        const int t  = tb >> 5;
        const int b  = tb & 31;
        const size_t di = ((((size_t)t * 2 + (i >> 5)) * 4 + ((i >> 3) & 3)) * 32 + b) * 8 + (i & 7);
        xp[di] = (i < DIN) ? (f16)x[(size_t)tb * DIN + i] : (f16)0.f;
    }
    uint4v* hs4 = (uint4v*)hsent;
    const uint4v sv = {0xFFFFFFFFu, 0xFFFFFFFFu, 0xFFFFFFFFu, 0xFFFFFFFFu};
    const int n4 = (2 * 13107200) / 4;
    for (int idx = gid; idx < n4; idx += nth) hs4[idx] = sv;
    if (gid < 60) { sin_t[gid] = sinf(alphabet[gid]); cos_t[gid] = cosf(alphabet[gid]); }
}

// logits -> softmax -> dihedral angles (h2 packed [t][KT][q][b][8])
__global__ __launch_bounds__(640, 1) void head_kernel(
    const f16* __restrict__ h2, const float* __restrict__ Wl, const float* __restrict__ bl,
    const float* __restrict__ sin_t, const float* __restrict__ cos_t,
    float* __restrict__ angles) {
    __shared__ float pl[20][33];
    __shared__ float mx[32];
    const int t = blockIdx.x;
    const int a = threadIdx.x / 32;
    const int b = threadIdx.x & 31;
    if (a < 20) {
        float acc = bl[a];
        const float* wr = Wl + (size_t)a * KROW;
        const f16*   hr = h2 + (size_t)t * 50 * 4 * 32 * 8;
        for (int k8 = 0; k8 < KROW / 8; ++k8) {
            const half8 hv = *(const half8*)(hr + (((size_t)k8) * 32 + b) * 8);
#pragma unroll
            for (int j = 0; j < 8; ++j) acc = fmaf(wr[k8 * 8 + j], (float)hv[j], acc);
        }
        pl[a][b] = acc;
    }
    __syncthreads();
    if (threadIdx.x < 32) {
        float m = pl[0][threadIdx.x];
        for (int i = 1; i < 20; ++i) m = fmaxf(m, pl[i][threadIdx.x]);
        mx[threadIdx.x] = m;
    }
    __syncthreads();
    if (a < 20) pl[a][b] = expf(pl[a][b] - mx[b]);
    __syncthreads();
    if (threadIdx.x < 96) {
        const int c = threadIdx.x / 32, b2 = threadIdx.x & 31;
        float y = 0.f, xx = 0.f;
        for (int i = 0; i < 20; ++i) {
            const float e = pl[i][b2];
            y  = fmaf(e, sin_t[i * 3 + c], y);
            xx = fmaf(e, cos_t[i * 3 + c], xx);
        }
        angles[((size_t)t * BB + b2) * 3 + c] = atan2f(y, xx);
    }
}

// sequential NeRF coordinate extension, one lane per batch element
__global__ void coords_kernel(const float* __restrict__ angles, float* __restrict__ out) {
    const int b = threadIdx.x;
    if (b >= BB) return;
    const float rs[3]  = {1.458f, 1.525f, 1.33f};
    const float ths[3] = {2.124f, 1.941f, 2.028f};
    float ct[3], st[3];
#pragma unroll
    for (int k = 0; k < 3; ++k) { ct[k] = cosf(ths[k]); st[k] = sinf(ths[k]); }
    float pax = 0.f,     pay = 0.f, paz = 0.f;
    float pbx = 1.458f,  pby = 0.f, pbz = 0.f;
    float pcx = 2.f,     pcy = 1.f, pcz = 0.f;
    for (int n = 0; n < 3 * TT; ++n) {
        const int t = n / 3;
        const int k = n - 3 * t;
        const float phi = angles[((size_t)t * BB + b) * 3 + k];
        float ux = pcx - pbx, uy = pcy - pby, uz = pcz - pbz;
        const float il = rsqrtf(ux * ux + uy * uy + uz * uz);
        const float bcx = ux * il, bcy = uy * il, bcz = uz * il;
        const float wx = pbx - pax, wy = pby - pay, wz = pbz - paz;
        float cx = wy * bcz - wz * bcy, cy = wz * bcx - wx * bcz, cz = wx * bcy - wy * bcx;
        const float iln = rsqrtf(cx * cx + cy * cy + cz * cz);
        const float nx = cx * iln, ny = cy * iln, nz = cz * iln;
        const float mxv = ny * bcz - nz * bcy, myv = nz * bcx - nx * bcz, mzv = nx * bcy - ny * bcx;
        float sp, cp;
        __sincosf(phi, &sp, &cp);
        const float rr = rs[k], cth = ct[k], sth = st[k];
        const float dx = pcx - rr * cth * bcx + rr * sth * (cp * mxv + sp * nx);
        const float dy = pcy - rr * cth * bcy + rr * sth * (cp * myv + sp * ny);
        const float dz = pcz - rr * cth * bcz + rr * sth * (cp * mzv + sp * nz);
        float* o = out + ((size_t)n * BB + b) * 3;
        o[0] = dx; o[1] = dy; o[2] = dz;
        pax = pbx; pay = pby; paz = pbz;
        pbx = pcx; pby = pcy; pbz = pcz;
        pcx = dx;  pcy = dy;  pcz = dz;
    }
}

// ---------------------------------------------------------------------------
extern "C" void kernel_launch(void* const* d_in, const int* in_sizes, int n_in,
                              void* d_out, int out_size, void* d_ws, size_t ws_size,
                              hipStream_t stream) {
    (void)in_sizes; (void)n_in; (void)out_size; (void)ws_size;
    const float* x      = (const float*)d_in[0];
    const float* Wih_f0 = (const float*)d_in[1];
    const float* Whh_f0 = (const float*)d_in[2];
    const float* b_f0   = (const float*)d_in[3];
    const float* Wih_b0 = (const float*)d_in[4];
    const float* Whh_b0 = (const float*)d_in[5];
    const float* b_b0   = (const float*)d_in[6];
    const float* Wih_f1 = (const float*)d_in[7];
    const float* Whh_f1 = (const float*)d_in[8];
    const float* b_f1   = (const float*)d_in[9];
    const float* Wih_b1 = (const float*)d_in[10];
    const float* Whh_b1 = (const float*)d_in[11];
    const float* b_b1   = (const float*)d_in[12];
    const float* Wl     = (const float*)d_in[13];
    const float* bl     = (const float*)d_in[14];
    const float* alphabet = (const float*)d_in[15];

    float* ws = (float*)d_ws;
    f16*   xp     = (f16*)(ws + OFF_XT);
    f16*   h1     = (f16*)(ws + OFF_H1);
    f16*   h2     = (f16*)(ws + OFF_H2);
    float* angles = ws + OFF_ANG;
    float* sin_t  = ws + OFF_SIN;
    float* cos_t  = ws + OFF_COS;

    prep_kernel<<<1024, 256, 0, stream>>>(x, alphabet, xp, sin_t, cos_t, (unsigned*)(ws + OFF_H1));
    rnn0_kernel<<<100, 512, 0, stream>>>(xp, h1,
        Wih_f0, Whh_f0, b_f0, Wih_b0, Whh_b0, b_b0);
    rnn1_kernel<<<100, 512, 0, stream>>>(h1, h2,
        Wih_f1, Whh_f1, b_f1, Wih_b1, Whh_b1, b_b1);
    head_kernel<<<TT, 640, 0, stream>>>(h2, Wl, bl, sin_t, cos_t, angles);
    coords_kernel<<<1, 64, 0, stream>>>(angles, (float*)d_out);
}

// Round 8
// 6188.720 us; speedup vs baseline: 1.2280x; 1.2280x over previous
//
#include <hip/hip_runtime.h>
#include <math.h>

// ---------------------------------------------------------------------------
// RGN round 13: revert to R10 geometry (best, 4455us) + chain-latency micros.
//   R11 (canary) and R12 (fat blocks) both falsified congestion/straggler
//   theories -> the floor is chain latency: store->LLC visibility + detect
//   quantization + epilogue. This round:
//   (1) dual-generation polling: two in-flight read generations checked
//       alternately -> detect period ~RTT/2 instead of ~RTT.
//   (2) __expf-based sigmoid/tanh (saturation-safe) in the epilogue.
//   (3) tail: float4 Wl loads in head; prefetched angles in coords.
//   Geometry: 100 blocks/dir, 8 units/block, 8 waves, K-split 8,
//   hp[t][KT][q][b][8] fragment-order layout, sentinel 0xFFFF, relaxed
//   agent-scope u64 LLC traffic, no fences/flags/barriers.
// ---------------------------------------------------------------------------

#define TT 512
#define BB 32
#define HH 800
#define DIN 41
#define KROW 1600

typedef _Float16 f16;
typedef _Float16 half8 __attribute__((ext_vector_type(8)));
typedef float floatx4 __attribute__((ext_vector_type(4)));
typedef unsigned uint4v __attribute__((ext_vector_type(4)));

// ---------------- workspace layout (float-slot offsets) --------------------
#define OFF_XT   8192                       // xp f16 [512][2][4][32][8]
#define OFF_H1   (OFF_XT + 524288)          // hp1 f16 [512][50][4][32][8]
#define OFF_H2   (OFF_H1 + 13107200)        // hp2 f16 [512][50][4][32][8]
#define OFF_ANG  (OFF_H2 + 13107200)        // f32 [512][32][3]
#define OFF_SIN  (OFF_ANG + 49152)
#define OFF_COS  (OFF_SIN + 64)

#define SENT 0xFFFFFFFFFFFFFFFFull

// fast, saturation-safe activations (f16 output precision is ample)
__device__ __forceinline__ float sigm(float x) { return 1.0f / (1.0f + __expf(-x)); }
__device__ __forceinline__ float ftanh(float x) {
    const float t = __expf(-2.0f * fabsf(x));     // in (0,1], no overflow
    const float r = (1.0f - t) / (1.0f + t);
    return copysignf(r, x);
}

union U64H8 { unsigned long long u[2]; half8 h; };

__device__ __forceinline__ unsigned long long ald8(const f16* p) {
    return __hip_atomic_load((const unsigned long long*)p, __ATOMIC_RELAXED, __HIP_MEMORY_SCOPE_AGENT);
}
__device__ __forceinline__ void ast8(f16* p, unsigned long long v) {
    __hip_atomic_store((unsigned long long*)p, v, __ATOMIC_RELAXED, __HIP_MEMORY_SCOPE_AGENT);
}
__device__ __forceinline__ half8 cvt8(const float* p) {
    half8 r;
#pragma unroll
    for (int i = 0; i < 8; ++i) r[i] = (f16)p[i];
    return r;
}

// fragment-order index (in f16 units): hp[t][KT][q][b][0]
__device__ __forceinline__ size_t hpi(int t, int KT, int q, int b) {
    return ((((size_t)t * 50 + KT) * 4 + q) * 32 + b) * 8;
}

// ===========================================================================
// rnn0: layer 0. 100 blocks/dir, 8 units/block, 8 waves. 27 k-tiles strided
// kt = w + 8*i (i<4). kt<2: x (cached, packed); 2<=kt<27: h1 prev (bypass).
// ===========================================================================
__global__ __launch_bounds__(512, 1) void rnn0_kernel(
    const f16* __restrict__ xp, f16* __restrict__ h1,
    const float* __restrict__ Wih_f0, const float* __restrict__ Whh_f0, const float* __restrict__ b_f0,
    const float* __restrict__ Wih_b0, const float* __restrict__ Whh_b0, const float* __restrict__ b_b0)
{
    __shared__ float gbuf[8][32][34];
    __shared__ f16  hbuf[256];

    const int tid  = threadIdx.x;
    const int w    = tid >> 6;          // 0..7
    const int lane = tid & 63;
    const int l15  = lane & 15;
    const int quad = lane >> 4;
    const int dir  = blockIdx.x / 100;
    const int blk  = blockIdx.x % 100;
    const int j0   = blk * 8;
    const int jl   = tid >> 5;          // epilogue: hidden unit (tid<256 -> 0..7)
    const int bb   = tid & 31;          // epilogue: batch

    const float* Wih = dir ? Wih_b0 : Wih_f0;
    const float* Whh = dir ? Whh_b0 : Whh_f0;
    const float* bs  = dir ? b_b0  : b_f0;

    half8 afr[2][4];
#pragma unroll
    for (int mt = 0; mt < 2; ++mt) {
        const int r = mt * 16 + l15;
        const int grow = (r >> 3) * HH + j0 + (r & 7);
#pragma unroll
        for (int i = 0; i < 4; ++i) {
            const int kt = w + 8 * i;
            half8 v;
#pragma unroll
            for (int jj = 0; jj < 8; ++jj) v[jj] = (f16)0.f;
            if (kt < 27) {
                if (kt < 2) {
#pragma unroll
                    for (int jj = 0; jj < 8; ++jj) {
                        const int k = kt * 32 + quad * 8 + jj;
                        if (k < DIN) v[jj] = (f16)Wih[(size_t)grow * DIN + k];
                    }
                } else {
                    v = cvt8(Whh + (size_t)grow * HH + (kt - 2) * 32 + quad * 8);
                }
            }
            afr[mt][i] = v;
        }
    }
    const float bi = bs[0 * HH + j0 + jl], bf = bs[1 * HH + j0 + jl],
                bg = bs[2 * HH + j0 + jl], bo = bs[3 * HH + j0 + jl];

    const int KT0 = dir * 25 + (blk >> 2);
    const int q0  = blk & 3;

    // phase-A prefetch registers (x tile, waves 0,1 only)
    half8 px0, px1;
    {
        const int t0 = dir ? (TT - 1) : 0;
        if (w < 2) {
            const f16* p = xp + ((((size_t)t0 * 2 + w) * 4 + quad) * 32) * 8;
            px0 = *(const half8*)(p + (size_t)l15 * 8);
            px1 = *(const half8*)(p + (size_t)(16 + l15) * 8);
        }
    }

    float creg = 0.0f;
    for (int s = 0; s < TT; ++s) {
        const int t  = dir ? (TT - 1 - s) : s;
        const int tp = dir ? t + 1 : t - 1;
        const int tn = dir ? (t > 0 ? t - 1 : 0) : (t < TT - 1 ? t + 1 : t);

        // ---- (1) gen-A prefetch of bypass tiles ----
        U64H8 rb[4][2];
        if (s > 0) {
#pragma unroll
            for (int i = 0; i < 4; ++i) {
                const int kt = w + 8 * i;
                if (kt >= 2 && kt < 27) {
                    const f16* p = h1 + hpi(tp, dir * 25 + (kt - 2), quad, 0);
                    rb[i][0].u[0] = ald8(p + (size_t)l15 * 8);
                    rb[i][0].u[1] = ald8(p + (size_t)l15 * 8 + 4);
                    rb[i][1].u[0] = ald8(p + (size_t)(16 + l15) * 8);
                    rb[i][1].u[1] = ald8(p + (size_t)(16 + l15) * 8 + 4);
                }
            }
        }

        floatx4 acc[2][2];
        acc[0][0] = (floatx4)0.f; acc[0][1] = (floatx4)0.f;
        acc[1][0] = (floatx4)0.f; acc[1][1] = (floatx4)0.f;

        // ---- (2) phase A: x tile MFMA from prefetched regs (waves 0,1) ----
        if (w < 2) {
            acc[0][0] = __builtin_amdgcn_mfma_f32_16x16x32_f16(afr[0][0], px0, acc[0][0], 0, 0, 0);
            acc[0][1] = __builtin_amdgcn_mfma_f32_16x16x32_f16(afr[0][0], px1, acc[0][1], 0, 0, 0);
            acc[1][0] = __builtin_amdgcn_mfma_f32_16x16x32_f16(afr[1][0], px0, acc[1][0], 0, 0, 0);
            acc[1][1] = __builtin_amdgcn_mfma_f32_16x16x32_f16(afr[1][0], px1, acc[1][1], 0, 0, 0);
            const f16* p = xp + ((((size_t)tn * 2 + w) * 4 + quad) * 32) * 8;
            px0 = *(const half8*)(p + (size_t)l15 * 8);
            px1 = *(const half8*)(p + (size_t)(16 + l15) * 8);
        }

        // ---- (3) phase B: dual-generation verify ----
        if (s > 0) {
            // gen-B issue (staggered ~phase-A-time after gen-A)
            U64H8 rc[4][2];
#pragma unroll
            for (int i = 0; i < 4; ++i) {
                const int kt = w + 8 * i;
                if (kt >= 2 && kt < 27) {
                    const f16* p = h1 + hpi(tp, dir * 25 + (kt - 2), quad, 0);
                    rc[i][0].u[0] = ald8(p + (size_t)l15 * 8);
                    rc[i][0].u[1] = ald8(p + (size_t)l15 * 8 + 4);
                    rc[i][1].u[0] = ald8(p + (size_t)(16 + l15) * 8);
                    rc[i][1].u[1] = ald8(p + (size_t)(16 + l15) * 8 + 4);
                }
            }
            for (;;) {
                // check gen-A
                int dm = 0;
#pragma unroll
                for (int i = 0; i < 4; ++i) {
                    const int kt = w + 8 * i;
                    if (kt >= 2 && kt < 27)
                        dm |= (rb[i][0].u[0] == SENT) | (rb[i][0].u[1] == SENT) |
                              (rb[i][1].u[0] == SENT) | (rb[i][1].u[1] == SENT);
                }
                if (!__any(dm)) break;
                // reissue gen-A
#pragma unroll
                for (int i = 0; i < 4; ++i) {
                    const int kt = w + 8 * i;
                    if (kt >= 2 && kt < 27) {
                        const f16* p = h1 + hpi(tp, dir * 25 + (kt - 2), quad, 0);
                        rb[i][0].u[0] = ald8(p + (size_t)l15 * 8);
                        rb[i][0].u[1] = ald8(p + (size_t)l15 * 8 + 4);
                        rb[i][1].u[0] = ald8(p + (size_t)(16 + l15) * 8);
                        rb[i][1].u[1] = ald8(p + (size_t)(16 + l15) * 8 + 4);
                    }
                }
                // check gen-B (already ~RTT/2 in flight)
                int dmc = 0;
#pragma unroll
                for (int i = 0; i < 4; ++i) {
                    const int kt = w + 8 * i;
                    if (kt >= 2 && kt < 27)
                        dmc |= (rc[i][0].u[0] == SENT) | (rc[i][0].u[1] == SENT) |
                               (rc[i][1].u[0] == SENT) | (rc[i][1].u[1] == SENT);
                }
                if (!__any(dmc)) {
#pragma unroll
                    for (int i = 0; i < 4; ++i) { rb[i][0] = rc[i][0]; rb[i][1] = rc[i][1]; }
                    break;
                }
                // reissue gen-B
#pragma unroll
                for (int i = 0; i < 4; ++i) {
                    const int kt = w + 8 * i;
                    if (kt >= 2 && kt < 27) {
                        const f16* p = h1 + hpi(tp, dir * 25 + (kt - 2), quad, 0);
                        rc[i][0].u[0] = ald8(p + (size_t)l15 * 8);
                        rc[i][0].u[1] = ald8(p + (size_t)l15 * 8 + 4);
                        rc[i][1].u[0] = ald8(p + (size_t)(16 + l15) * 8);
                        rc[i][1].u[1] = ald8(p + (size_t)(16 + l15) * 8 + 4);
                    }
                }
            }
            // ---- phase B MFMA ----
#pragma unroll
            for (int i = 0; i < 4; ++i) {
                const int kt = w + 8 * i;
                if (kt >= 2 && kt < 27) {
                    acc[0][0] = __builtin_amdgcn_mfma_f32_16x16x32_f16(afr[0][i], rb[i][0].h, acc[0][0], 0, 0, 0);
                    acc[0][1] = __builtin_amdgcn_mfma_f32_16x16x32_f16(afr[0][i], rb[i][1].h, acc[0][1], 0, 0, 0);
                    acc[1][0] = __builtin_amdgcn_mfma_f32_16x16x32_f16(afr[1][i], rb[i][0].h, acc[1][0], 0, 0, 0);
                    acc[1][1] = __builtin_amdgcn_mfma_f32_16x16x32_f16(afr[1][i], rb[i][1].h, acc[1][1], 0, 0, 0);
                }
            }
        }

        // ---- (4) cross-wave reduce + epilogue ----
#pragma unroll
        for (int mt = 0; mt < 2; ++mt)
#pragma unroll
            for (int nt = 0; nt < 2; ++nt)
#pragma unroll
                for (int rg = 0; rg < 4; ++rg)
                    gbuf[w][mt * 16 + quad * 4 + rg][nt * 16 + l15] = acc[mt][nt][rg];
        __syncthreads();
        if (tid < 256) {
            float gi_ = bi, gf_ = bf, gc_ = bg, go_ = bo;
#pragma unroll
            for (int ww = 0; ww < 8; ++ww) {
                gi_ += gbuf[ww][jl][bb];
                gf_ += gbuf[ww][8 + jl][bb];
                gc_ += gbuf[ww][16 + jl][bb];
                go_ += gbuf[ww][24 + jl][bb];
            }
            const float cn = sigm(gf_) * creg + sigm(gi_) * ftanh(gc_);
            creg = cn;
            hbuf[bb * 8 + jl] = (f16)(sigm(go_) * ftanh(cn));
        }
        __syncthreads();
        if (tid < BB) {
            f16* dst = h1 + hpi(t, KT0, q0, tid);
            const unsigned long long* src = (const unsigned long long*)(hbuf + tid * 8);
            ast8(dst, src[0]);
            ast8(dst + 4, src[1]);
        }
    }
}

// ===========================================================================
// rnn1: layer 1. 100 blocks/dir, 8 units/block, 8 waves. 75 k-tiles strided
// kt = w + 8*i. kt<50 (i<7): h1[t] (cached); 50<=kt<75 (i in 6..9): h2 prev.
// ===========================================================================
__global__ __launch_bounds__(512, 1) void rnn1_kernel(
    const f16* __restrict__ h1, f16* __restrict__ h2,
    const float* __restrict__ Wih_f1, const float* __restrict__ Whh_f1, const float* __restrict__ b_f1,
    const float* __restrict__ Wih_b1, const float* __restrict__ Whh_b1, const float* __restrict__ b_b1)
{
    __shared__ float gbuf[8][32][34];
    __shared__ f16  hbuf[256];

    const int tid  = threadIdx.x;
    const int w    = tid >> 6;
    const int lane = tid & 63;
    const int l15  = lane & 15;
    const int quad = lane >> 4;
    const int dir  = blockIdx.x / 100;
    const int blk  = blockIdx.x % 100;
    const int j0   = blk * 8;
    const int jl   = tid >> 5;
    const int bb   = tid & 31;

    const float* Wih = dir ? Wih_b1 : Wih_f1;
    const float* Whh = dir ? Whh_b1 : Whh_f1;
    const float* bs  = dir ? b_b1  : b_f1;

    half8 afr[2][10];
#pragma unroll
    for (int mt = 0; mt < 2; ++mt) {
        const int r = mt * 16 + l15;
        const int grow = (r >> 3) * HH + j0 + (r & 7);
#pragma unroll
        for (int i = 0; i < 10; ++i) {
            const int kt = w + 8 * i;
            half8 v;
#pragma unroll
            for (int jj = 0; jj < 8; ++jj) v[jj] = (f16)0.f;
            if (kt < 75) {
                if (kt < 50) v = cvt8(Wih + (size_t)grow * KROW + kt * 32 + quad * 8);
                else         v = cvt8(Whh + (size_t)grow * HH + (kt - 50) * 32 + quad * 8);
            }
            afr[mt][i] = v;
        }
    }
    const float bi = bs[0 * HH + j0 + jl], bf = bs[1 * HH + j0 + jl],
                bg = bs[2 * HH + j0 + jl], bo = bs[3 * HH + j0 + jl];

    const int KT0 = dir * 25 + (blk >> 2);
    const int q0  = blk & 3;

    // phase-A prefetch registers: up to 7 tiles (kt = w+8i < 50)
    half8 pa[7][2];
    {
        const int t0 = dir ? (TT - 1) : 0;
#pragma unroll
        for (int i = 0; i < 7; ++i) {
            const int kt = w + 8 * i;
            if (kt < 50) {
                const f16* p = h1 + hpi(t0, kt, quad, 0);
                pa[i][0] = *(const half8*)(p + (size_t)l15 * 8);
                pa[i][1] = *(const half8*)(p + (size_t)(16 + l15) * 8);
            }
        }
    }

    float creg = 0.0f;
    for (int s = 0; s < TT; ++s) {
        const int t  = dir ? (TT - 1 - s) : s;
        const int tp = dir ? t + 1 : t - 1;
        const int tn = dir ? (t > 0 ? t - 1 : 0) : (t < TT - 1 ? t + 1 : t);

        // ---- (1) gen-A prefetch of bypass tiles ----
        U64H8 rb[4][2];
        if (s > 0) {
#pragma unroll
            for (int i = 6; i < 10; ++i) {
                const int kt = w + 8 * i;
                if (kt >= 50 && kt < 75) {
                    const f16* p = h2 + hpi(tp, dir * 25 + (kt - 50), quad, 0);
                    rb[i - 6][0].u[0] = ald8(p + (size_t)l15 * 8);
                    rb[i - 6][0].u[1] = ald8(p + (size_t)l15 * 8 + 4);
                    rb[i - 6][1].u[0] = ald8(p + (size_t)(16 + l15) * 8);
                    rb[i - 6][1].u[1] = ald8(p + (size_t)(16 + l15) * 8 + 4);
                }
            }
        }

        floatx4 acc[2][2];
        acc[0][0] = (floatx4)0.f; acc[0][1] = (floatx4)0.f;
        acc[1][0] = (floatx4)0.f; acc[1][1] = (floatx4)0.f;

        // ---- (2) phase A: h1[t] MFMA from prefetched regs ----
#pragma unroll
        for (int i = 0; i < 7; ++i) {
            const int kt = w + 8 * i;
            if (kt < 50) {
                acc[0][0] = __builtin_amdgcn_mfma_f32_16x16x32_f16(afr[0][i], pa[i][0], acc[0][0], 0, 0, 0);
                acc[0][1] = __builtin_amdgcn_mfma_f32_16x16x32_f16(afr[0][i], pa[i][1], acc[0][1], 0, 0, 0);
                acc[1][0] = __builtin_amdgcn_mfma_f32_16x16x32_f16(afr[1][i], pa[i][0], acc[1][0], 0, 0, 0);
                acc[1][1] = __builtin_amdgcn_mfma_f32_16x16x32_f16(afr[1][i], pa[i][1], acc[1][1], 0, 0, 0);
            }
        }

        // ---- (3) reload pa for next step (completes under phase-B wait) ----
#pragma unroll
        for (int i = 0; i < 7; ++i) {
            const int kt = w + 8 * i;
            if (kt < 50) {
                const f16* p = h1 + hpi(tn, kt, quad, 0);
                pa[i][0] = *(const half8*)(p + (size_t)l15 * 8);
                pa[i][1] = *(const half8*)(p + (size_t)(16 + l15) * 8);
            }
        }

        // ---- (4) phase B: dual-generation verify ----
        if (s > 0) {
            U64H8 rc[4][2];
#pragma unroll
            for (int i = 6; i < 10; ++i) {
                const int kt = w + 8 * i;
                if (kt >= 50 && kt < 75) {
                    const f16* p = h2 + hpi(tp, dir * 25 + (kt - 50), quad, 0);
                    rc[i - 6][0].u[0] = ald8(p + (size_t)l15 * 8);
                    rc[i - 6][0].u[1] = ald8(p + (size_t)l15 * 8 + 4);
                    rc[i - 6][1].u[0] = ald8(p + (size_t)(16 + l15) * 8);
                    rc[i - 6][1].u[1] = ald8(p + (size_t)(16 + l15) * 8 + 4);
                }
            }
            for (;;) {
                int dm = 0;
#pragma unroll
                for (int i = 6; i < 10; ++i) {
                    const int kt = w + 8 * i;
                    if (kt >= 50 && kt < 75)
                        dm |= (rb[i - 6][0].u[0] == SENT) | (rb[i - 6][0].u[1] == SENT) |
                              (rb[i - 6][1].u[0] == SENT) | (rb[i - 6][1].u[1] == SENT);
                }
                if (!__any(dm)) break;
#pragma unroll
                for (int i = 6; i < 10; ++i) {
                    const int kt = w + 8 * i;
                    if (kt >= 50 && kt < 75) {
                        const f16* p = h2 + hpi(tp, dir * 25 + (kt - 50), quad, 0);
                        rb[i - 6][0].u[0] = ald8(p + (size_t)l15 * 8);
                        rb[i - 6][0].u[1] = ald8(p + (size_t)l15 * 8 + 4);
                        rb[i - 6][1].u[0] = ald8(p + (size_t)(16 + l15) * 8);
                        rb[i - 6][1].u[1] = ald8(p + (size_t)(16 + l15) * 8 + 4);
                    }
                }
                int dmc = 0;
#pragma unroll
                for (int i = 6; i < 10; ++i) {
                    const int kt = w + 8 * i;
                    if (kt >= 50 && kt < 75)
                        dmc |= (rc[i - 6][0].u[0] == SENT) | (rc[i - 6][0].u[1] == SENT) |
                               (rc[i - 6][1].u[0] == SENT) | (rc[i - 6][1].u[1] == SENT);
                }
                if (!__any(dmc)) {
#pragma unroll
                    for (int i = 0; i < 4; ++i) { rb[i][0] = rc[i][0]; rb[i][1] = rc[i][1]; }
                    break;
                }
#pragma unroll
                for (int i = 6; i < 10; ++i) {
                    const int kt = w + 8 * i;
                    if (kt >= 50 && kt < 75) {
                        const f16* p = h2 + hpi(tp, dir * 25 + (kt - 50), quad, 0);
                        rc[i - 6][0].u[0] = ald8(p + (size_t)l15 * 8);
                        rc[i - 6][0].u[1] = ald8(p + (size_t)l15 * 8 + 4);
                        rc[i - 6][1].u[0] = ald8(p + (size_t)(16 + l15) * 8);
                        rc[i - 6][1].u[1] = ald8(p + (size_t)(16 + l15) * 8 + 4);
                    }
                }
            }
            // ---- phase B MFMA ----
#pragma unroll
            for (int i = 6; i < 10; ++i) {
                const int kt = w + 8 * i;
                if (kt >= 50 && kt < 75) {
                    acc[0][0] = __builtin_amdgcn_mfma_f32_16x16x32_f16(afr[0][i], rb[i - 6][0].h, acc[0][0], 0, 0, 0);
                    acc[0][1] = __builtin_amdgcn_mfma_f32_16x16x32_f16(afr[0][i], rb[i - 6][1].h, acc[0][1], 0, 0, 0);
                    acc[1][0] = __builtin_amdgcn_mfma_f32_16x16x32_f16(afr[1][i], rb[i - 6][0].h, acc[1][0], 0, 0, 0);
                    acc[1][1] = __builtin_amdgcn_mfma_f32_16x16x32_f16(afr[1][i], rb[i - 6][1].h, acc[1][1], 0, 0, 0);
                }
            }
        }

        // ---- (5) cross-wave reduce + epilogue ----
#pragma unroll
        for (int mt = 0; mt < 2; ++mt)
#pragma unroll
            for (int nt = 0; nt < 2; ++nt)
#pragma unroll
                for (int rg = 0; rg < 4; ++rg)
                    gbuf[w][mt * 16 + quad * 4 + rg][nt * 16 + l15] = acc[mt][nt][rg];
        __syncthreads();
        if (tid < 256) {
            float gi_ = bi, gf_ = bf, gc_ = bg, go_ = bo;
#pragma unroll
            for (int ww = 0; ww < 8; ++ww) {
                gi_ += gbuf[ww][jl][bb];
                gf_ += gbuf[ww][8 + jl][bb];
                gc_ += gbuf[ww][16 + jl][bb];
                go_ += gbuf[ww][24 + jl][bb];
            }
            const float cn = sigm(gf_) * creg + sigm(gi_) * ftanh(gc_);
            creg = cn;
            hbuf[bb * 8 + jl] = (f16)(sigm(go_) * ftanh(cn));
        }
        __syncthreads();
        if (tid < BB) {
            f16* dst = h2 + hpi(t, KT0, q0, tid);
            const unsigned long long* src = (const unsigned long long*)(hbuf + tid * 8);
            ast8(dst, src[0]);
            ast8(dst + 4, src[1]);
        }
    }
}

// ---------------------------------------------------------------------------
// prep: xp packed f16, sin/cos tables, sentinel-fill h1+h2 (105 MB)
__global__ void prep_kernel(const float* __restrict__ x, const float* __restrict__ alphabet,
                            f16* __restrict__ xp, float* __restrict__ sin_t,
                            float* __restrict__ cos_t, unsigned* __restrict__ hsent) {
    const int gid = blockIdx.x * blockDim.x + threadIdx.x;
    const int nth = gridDim.x * blockDim.x;
    for (int idx = gid; idx < TT * BB * 64; idx += nth) {
        const int tb = idx >> 6;            // t*32+b
        const int i  = idx & 63;
        const int t  = tb >> 5;
        const int b  = tb & 31;
        const size_t di = ((((size_t)t * 2 + (i >> 5)) * 4 + ((i >> 3) & 3)) * 32 + b) * 8 + (i & 7);
        xp[di] = (i < DIN) ? (f16)x[(size_t)tb * DIN + i] : (f16)0.f;
    }
    uint4v* hs4 = (uint4v*)hsent;
    const uint4v sv = {0xFFFFFFFFu, 0xFFFFFFFFu, 0xFFFFFFFFu, 0xFFFFFFFFu};
    const int n4 = (2 * 13107200) / 4;
    for (int idx = gid; idx < n4; idx += nth) hs4[idx] = sv;
    if (gid < 60) { sin_t[gid] = sinf(alphabet[gid]); cos_t[gid] = cosf(alphabet[gid]); }
}

// logits -> softmax -> dihedral angles (h2 packed [t][KT][q][b][8])
__global__ __launch_bounds__(640, 1) void head_kernel(
    const f16* __restrict__ h2, const float* __restrict__ Wl, const float* __restrict__ bl,
    const float* __restrict__ sin_t, const float* __restrict__ cos_t,
    float* __restrict__ angles) {
    __shared__ float pl[20][33];
    __shared__ float mx[32];
    const int t = blockIdx.x;
    const int a = threadIdx.x / 32;
    const int b = threadIdx.x & 31;
    if (a < 20) {
        float acc = bl[a];
        const float* wr = Wl + (size_t)a * KROW;
        const f16*   hr = h2 + (size_t)t * 50 * 4 * 32 * 8;
        for (int k8 = 0; k8 < KROW / 8; ++k8) {
            const half8 hv = *(const half8*)(hr + (((size_t)k8) * 32 + b) * 8);
            const float4 w0 = *(const float4*)(wr + k8 * 8);
            const float4 w1 = *(const float4*)(wr + k8 * 8 + 4);
            acc = fmaf(w0.x, (float)hv[0], acc);
            acc = fmaf(w0.y, (float)hv[1], acc);
            acc = fmaf(w0.z, (float)hv[2], acc);
            acc = fmaf(w0.w, (float)hv[3], acc);
            acc = fmaf(w1.x, (float)hv[4], acc);
            acc = fmaf(w1.y, (float)hv[5], acc);
            acc = fmaf(w1.z, (float)hv[6], acc);
            acc = fmaf(w1.w, (float)hv[7], acc);
        }
        pl[a][b] = acc;
    }
    __syncthreads();
    if (threadIdx.x < 32) {
        float m = pl[0][threadIdx.x];
        for (int i = 1; i < 20; ++i) m = fmaxf(m, pl[i][threadIdx.x]);
        mx[threadIdx.x] = m;
    }
    __syncthreads();
    if (a < 20) pl[a][b] = __expf(pl[a][b] - mx[b]);
    __syncthreads();
    if (threadIdx.x < 96) {
        const int c = threadIdx.x / 32, b2 = threadIdx.x & 31;
        float y = 0.f, xx = 0.f;
        for (int i = 0; i < 20; ++i) {
            const float e = pl[i][b2];
            y  = fmaf(e, sin_t[i * 3 + c], y);
            xx = fmaf(e, cos_t[i * 3 + c], xx);
        }
        angles[((size_t)t * BB + b2) * 3 + c] = atan2f(y, xx);
    }
}

// sequential NeRF coordinate extension, one lane per batch element.
// angles loads software-prefetched one iteration ahead (latency hiding).
__global__ void coords_kernel(const float* __restrict__ angles, float* __restrict__ out) {
    const int b = threadIdx.x;
    if (b >= BB) return;
    const float rs[3]  = {1.458f, 1.525f, 1.33f};
    const float ths[3] = {2.124f, 1.941f, 2.028f};
    float ct[3], st[3];
#pragma unroll
    for (int k = 0; k < 3; ++k) { ct[k] = cosf(ths[k]); st[k] = sinf(ths[k]); }
    float pax = 0.f,     pay = 0.f, paz = 0.f;
    float pbx = 1.458f,  pby = 0.f, pbz = 0.f;
    float pcx = 2.f,     pcy = 1.f, pcz = 0.f;
    // phi address for (t,k): t*96 + b*3 + k
    float phi_next = angles[(size_t)b * 3];
    for (int n = 0; n < 3 * TT; ++n) {
        const float phi = phi_next;
        if (n + 1 < 3 * TT) {
            const int t2 = (n + 1) / 3;
            const int k2 = (n + 1) - 3 * t2;
            phi_next = angles[(size_t)t2 * 96 + b * 3 + k2];
        }
        float ux = pcx - pbx, uy = pcy - pby, uz = pcz - pbz;
        const float il = rsqrtf(ux * ux + uy * uy + uz * uz);
        const float bcx = ux * il, bcy = uy * il, bcz = uz * il;
        const float wx = pbx - pax, wy = pby - pay, wz = pbz - paz;
        float cx = wy * bcz - wz * bcy, cy = wz * bcx - wx * bcz, cz = wx * bcy - wy * bcx;
        const float iln = rsqrtf(cx * cx + cy * cy + cz * cz);
        const float nx = cx * iln, ny = cy * iln, nz = cz * iln;
        const float mxv = ny * bcz - nz * bcy, myv = nz * bcx - nx * bcz, mzv = nx * bcy - ny * bcx;
        float sp, cp;
        __sincosf(phi, &sp, &cp);
        const int k = n - 3 * (n / 3);
        const float rr = rs[k], cth = ct[k], sth = st[k];
        const float dx = pcx - rr * cth * bcx + rr * sth * (cp * mxv + sp * nx);
        const float dy = pcy - rr * cth * bcy + rr * sth * (cp * myv + sp * ny);
        const float dz = pcz - rr * cth * bcz + rr * sth * (cp * mzv + sp * nz);
        float* o = out + ((size_t)n * BB + b) * 3;
        o[0] = dx; o[1] = dy; o[2] = dz;
        pax = pbx; pay = pby; paz = pbz;
        pbx = pcx; pby = pcy; pbz = pcz;
        pcx = dx;  pcy = dy;  pcz = dz;
    }
}

// ---------------------------------------------------------------------------
extern "C" void kernel_launch(void* const* d_in, const int* in_sizes, int n_in,
                              void* d_out, int out_size, void* d_ws, size_t ws_size,
                              hipStream_t stream) {
    (void)in_sizes; (void)n_in; (void)out_size; (void)ws_size;
    const float* x      = (const float*)d_in[0];
    const float* Wih_f0 = (const float*)d_in[1];
    const float* Whh_f0 = (const float*)d_in[2];
    const float* b_f0   = (const float*)d_in[3];
    const float* Wih_b0 = (const float*)d_in[4];
    const float* Whh_b0 = (const float*)d_in[5];
    const float* b_b0   = (const float*)d_in[6];
    const float* Wih_f1 = (const float*)d_in[7];
    const float* Whh_f1 = (const float*)d_in[8];
    const float* b_f1   = (const float*)d_in[9];
    const float* Wih_b1 = (const float*)d_in[10];
    const float* Whh_b1 = (const float*)d_in[11];
    const float* b_b1   = (const float*)d_in[12];
    const float* Wl     = (const float*)d_in[13];
    const float* bl     = (const float*)d_in[14];
    const float* alphabet = (const float*)d_in[15];

    float* ws = (float*)d_ws;
    f16*   xp     = (f16*)(ws + OFF_XT);
    f16*   h1     = (f16*)(ws + OFF_H1);
    f16*   h2     = (f16*)(ws + OFF_H2);
    float* angles = ws + OFF_ANG;
    float* sin_t  = ws + OFF_SIN;
    float* cos_t  = ws + OFF_COS;

    prep_kernel<<<1024, 256, 0, stream>>>(x, alphabet, xp, sin_t, cos_t, (unsigned*)(ws + OFF_H1));
    rnn0_kernel<<<200, 512, 0, stream>>>(xp, h1,
        Wih_f0, Whh_f0, b_f0, Wih_b0, Whh_b0, b_b0);
    rnn1_kernel<<<200, 512, 0, stream>>>(h1, h2,
        Wih_f1, Whh_f1, b_f1, Wih_b1, Whh_b1, b_b1);
    head_kernel<<<TT, 640, 0, stream>>>(h2, Wl, bl, sin_t, cos_t, angles);
    coords_kernel<<<1, 64, 0, stream>>>(angles, (float*)d_out);
}

// Round 9
// 4367.133 us; speedup vs baseline: 1.7403x; 1.4171x over previous
//
#include <hip/hip_runtime.h>
#include <math.h>

// ---------------------------------------------------------------------------
// RGN round 14: restore R10 (best, 4455us) exactly; keep only off-critical-path
// micros from R13 (fast activations, head float4, coords prefetch).
//   Evidence: R11 (probe traffic down), R12 (fewer blocks), R13 (dual-gen
//   polling) ALL regressed -> R10's bulk-respin structure is the local optimum;
//   the full re-read IS both detect and fetch in one LLC RTT.
//   Geometry: 100 blocks/dir, 8 units/block, 8 waves, K-split 8,
//   hp[t][KT][q][b][8] fragment-order layout, sentinel 0xFFFF, relaxed
//   agent-scope u64 LLC traffic, no fences/flags/barriers.
// ---------------------------------------------------------------------------

#define TT 512
#define BB 32
#define HH 800
#define DIN 41
#define KROW 1600

typedef _Float16 f16;
typedef _Float16 half8 __attribute__((ext_vector_type(8)));
typedef float floatx4 __attribute__((ext_vector_type(4)));
typedef unsigned uint4v __attribute__((ext_vector_type(4)));

// ---------------- workspace layout (float-slot offsets) --------------------
#define OFF_XT   8192                       // xp f16 [512][2][4][32][8]
#define OFF_H1   (OFF_XT + 524288)          // hp1 f16 [512][50][4][32][8]
#define OFF_H2   (OFF_H1 + 13107200)        // hp2 f16 [512][50][4][32][8]
#define OFF_ANG  (OFF_H2 + 13107200)        // f32 [512][32][3]
#define OFF_SIN  (OFF_ANG + 49152)
#define OFF_COS  (OFF_SIN + 64)

#define SENT 0xFFFFFFFFFFFFFFFFull

// fast, saturation-safe activations (f16 output precision is ample)
__device__ __forceinline__ float sigm(float x) { return 1.0f / (1.0f + __expf(-x)); }
__device__ __forceinline__ float ftanh(float x) {
    const float t = __expf(-2.0f * fabsf(x));     // in (0,1], no overflow
    const float r = (1.0f - t) / (1.0f + t);
    return copysignf(r, x);
}

union U64H8 { unsigned long long u[2]; half8 h; };

__device__ __forceinline__ unsigned long long ald8(const f16* p) {
    return __hip_atomic_load((const unsigned long long*)p, __ATOMIC_RELAXED, __HIP_MEMORY_SCOPE_AGENT);
}
__device__ __forceinline__ void ast8(f16* p, unsigned long long v) {
    __hip_atomic_store((unsigned long long*)p, v, __ATOMIC_RELAXED, __HIP_MEMORY_SCOPE_AGENT);
}
__device__ __forceinline__ half8 cvt8(const float* p) {
    half8 r;
#pragma unroll
    for (int i = 0; i < 8; ++i) r[i] = (f16)p[i];
    return r;
}

// fragment-order index (in f16 units): hp[t][KT][q][b][0]
__device__ __forceinline__ size_t hpi(int t, int KT, int q, int b) {
    return ((((size_t)t * 50 + KT) * 4 + q) * 32 + b) * 8;
}

// ===========================================================================
// rnn0: layer 0. 100 blocks/dir, 8 units/block, 8 waves. 27 k-tiles strided
// kt = w + 8*i (i<4). kt<2: x (cached, packed); 2<=kt<27: h1 prev (bypass).
// ===========================================================================
__global__ __launch_bounds__(512, 1) void rnn0_kernel(
    const f16* __restrict__ xp, f16* __restrict__ h1,
    const float* __restrict__ Wih_f0, const float* __restrict__ Whh_f0, const float* __restrict__ b_f0,
    const float* __restrict__ Wih_b0, const float* __restrict__ Whh_b0, const float* __restrict__ b_b0)
{
    __shared__ float gbuf[8][32][34];
    __shared__ f16  hbuf[256];

    const int tid  = threadIdx.x;
    const int w    = tid >> 6;          // 0..7
    const int lane = tid & 63;
    const int l15  = lane & 15;
    const int quad = lane >> 4;
    const int dir  = blockIdx.x / 100;
    const int blk  = blockIdx.x % 100;
    const int j0   = blk * 8;
    const int jl   = tid >> 5;          // epilogue: hidden unit (tid<256 -> 0..7)
    const int bb   = tid & 31;          // epilogue: batch

    const float* Wih = dir ? Wih_b0 : Wih_f0;
    const float* Whh = dir ? Whh_b0 : Whh_f0;
    const float* bs  = dir ? b_b0  : b_f0;

    half8 afr[2][4];
#pragma unroll
    for (int mt = 0; mt < 2; ++mt) {
        const int r = mt * 16 + l15;
        const int grow = (r >> 3) * HH + j0 + (r & 7);
#pragma unroll
        for (int i = 0; i < 4; ++i) {
            const int kt = w + 8 * i;
            half8 v;
#pragma unroll
            for (int jj = 0; jj < 8; ++jj) v[jj] = (f16)0.f;
            if (kt < 27) {
                if (kt < 2) {
#pragma unroll
                    for (int jj = 0; jj < 8; ++jj) {
                        const int k = kt * 32 + quad * 8 + jj;
                        if (k < DIN) v[jj] = (f16)Wih[(size_t)grow * DIN + k];
                    }
                } else {
                    v = cvt8(Whh + (size_t)grow * HH + (kt - 2) * 32 + quad * 8);
                }
            }
            afr[mt][i] = v;
        }
    }
    const float bi = bs[0 * HH + j0 + jl], bf = bs[1 * HH + j0 + jl],
                bg = bs[2 * HH + j0 + jl], bo = bs[3 * HH + j0 + jl];

    const int KT0 = dir * 25 + (blk >> 2);
    const int q0  = blk & 3;

    // phase-A prefetch registers (x tile, waves 0,1 only)
    half8 px0, px1;
    {
        const int t0 = dir ? (TT - 1) : 0;
        if (w < 2) {
            const f16* p = xp + ((((size_t)t0 * 2 + w) * 4 + quad) * 32) * 8;
            px0 = *(const half8*)(p + (size_t)l15 * 8);
            px1 = *(const half8*)(p + (size_t)(16 + l15) * 8);
        }
    }

    float creg = 0.0f;
    for (int s = 0; s < TT; ++s) {
        const int t  = dir ? (TT - 1 - s) : s;
        const int tp = dir ? t + 1 : t - 1;
        const int tn = dir ? (t > 0 ? t - 1 : 0) : (t < TT - 1 ? t + 1 : t);

        // ---- (1) early prefetch of bypass tiles (hides LLC RTT) ----
        U64H8 rb[4][2];
        if (s > 0) {
#pragma unroll
            for (int i = 0; i < 4; ++i) {
                const int kt = w + 8 * i;
                if (kt >= 2 && kt < 27) {
                    const f16* p = h1 + hpi(tp, dir * 25 + (kt - 2), quad, 0);
                    rb[i][0].u[0] = ald8(p + (size_t)l15 * 8);
                    rb[i][0].u[1] = ald8(p + (size_t)l15 * 8 + 4);
                    rb[i][1].u[0] = ald8(p + (size_t)(16 + l15) * 8);
                    rb[i][1].u[1] = ald8(p + (size_t)(16 + l15) * 8 + 4);
                }
            }
        }

        floatx4 acc[2][2];
        acc[0][0] = (floatx4)0.f; acc[0][1] = (floatx4)0.f;
        acc[1][0] = (floatx4)0.f; acc[1][1] = (floatx4)0.f;

        // ---- (2) phase A: x tile MFMA from prefetched regs (waves 0,1) ----
        if (w < 2) {
            acc[0][0] = __builtin_amdgcn_mfma_f32_16x16x32_f16(afr[0][0], px0, acc[0][0], 0, 0, 0);
            acc[0][1] = __builtin_amdgcn_mfma_f32_16x16x32_f16(afr[0][0], px1, acc[0][1], 0, 0, 0);
            acc[1][0] = __builtin_amdgcn_mfma_f32_16x16x32_f16(afr[1][0], px0, acc[1][0], 0, 0, 0);
            acc[1][1] = __builtin_amdgcn_mfma_f32_16x16x32_f16(afr[1][0], px1, acc[1][1], 0, 0, 0);
            // reload px for next step (completes under phase-B wait)
            const f16* p = xp + ((((size_t)tn * 2 + w) * 4 + quad) * 32) * 8;
            px0 = *(const half8*)(p + (size_t)l15 * 8);
            px1 = *(const half8*)(p + (size_t)(16 + l15) * 8);
        }

        // ---- (3) phase B: bulk verify + bulk respin ----
        if (s > 0) {
            int dm = 0;
#pragma unroll
            for (int i = 0; i < 4; ++i) {
                const int kt = w + 8 * i;
                if (kt >= 2 && kt < 27) {
                    const int bad = (rb[i][0].u[0] == SENT) | (rb[i][0].u[1] == SENT) |
                                    (rb[i][1].u[0] == SENT) | (rb[i][1].u[1] == SENT);
                    dm |= bad << i;
                }
            }
            while (__any(dm != 0)) {
#pragma unroll
                for (int i = 0; i < 4; ++i) {
                    const int kt = w + 8 * i;
                    if (kt >= 2 && kt < 27) {
                        if (dm & (1 << i)) {
                            const f16* p = h1 + hpi(tp, dir * 25 + (kt - 2), quad, 0);
                            rb[i][0].u[0] = ald8(p + (size_t)l15 * 8);
                            rb[i][0].u[1] = ald8(p + (size_t)l15 * 8 + 4);
                            rb[i][1].u[0] = ald8(p + (size_t)(16 + l15) * 8);
                            rb[i][1].u[1] = ald8(p + (size_t)(16 + l15) * 8 + 4);
                        }
                    }
                }
                int nm = 0;
#pragma unroll
                for (int i = 0; i < 4; ++i) {
                    const int kt = w + 8 * i;
                    if (kt >= 2 && kt < 27) {
                        if (dm & (1 << i)) {
                            const int bad = (rb[i][0].u[0] == SENT) | (rb[i][0].u[1] == SENT) |
                                            (rb[i][1].u[0] == SENT) | (rb[i][1].u[1] == SENT);
                            nm |= bad << i;
                        }
                    }
                }
                dm = nm;
            }
            // ---- phase B MFMA ----
#pragma unroll
            for (int i = 0; i < 4; ++i) {
                const int kt = w + 8 * i;
                if (kt >= 2 && kt < 27) {
                    acc[0][0] = __builtin_amdgcn_mfma_f32_16x16x32_f16(afr[0][i], rb[i][0].h, acc[0][0], 0, 0, 0);
                    acc[0][1] = __builtin_amdgcn_mfma_f32_16x16x32_f16(afr[0][i], rb[i][1].h, acc[0][1], 0, 0, 0);
                    acc[1][0] = __builtin_amdgcn_mfma_f32_16x16x32_f16(afr[1][i], rb[i][0].h, acc[1][0], 0, 0, 0);
                    acc[1][1] = __builtin_amdgcn_mfma_f32_16x16x32_f16(afr[1][i], rb[i][1].h, acc[1][1], 0, 0, 0);
                }
            }
        }

        // ---- (4) cross-wave reduce + epilogue ----
#pragma unroll
        for (int mt = 0; mt < 2; ++mt)
#pragma unroll
            for (int nt = 0; nt < 2; ++nt)
#pragma unroll
                for (int rg = 0; rg < 4; ++rg)
                    gbuf[w][mt * 16 + quad * 4 + rg][nt * 16 + l15] = acc[mt][nt][rg];
        __syncthreads();
        if (tid < 256) {
            float gi_ = bi, gf_ = bf, gc_ = bg, go_ = bo;
#pragma unroll
            for (int ww = 0; ww < 8; ++ww) {
                gi_ += gbuf[ww][jl][bb];
                gf_ += gbuf[ww][8 + jl][bb];
                gc_ += gbuf[ww][16 + jl][bb];
                go_ += gbuf[ww][24 + jl][bb];
            }
            const float cn = sigm(gf_) * creg + sigm(gi_) * ftanh(gc_);
            creg = cn;
            hbuf[bb * 8 + jl] = (f16)(sigm(go_) * ftanh(cn));
        }
        __syncthreads();
        if (tid < BB) {
            f16* dst = h1 + hpi(t, KT0, q0, tid);
            const unsigned long long* src = (const unsigned long long*)(hbuf + tid * 8);
            ast8(dst, src[0]);
            ast8(dst + 4, src[1]);
        }
    }
}

// ===========================================================================
// rnn1: layer 1. 100 blocks/dir, 8 units/block, 8 waves. 75 k-tiles strided
// kt = w + 8*i. kt<50 (i<7): h1[t] (cached); 50<=kt<75 (i in 6..9): h2 prev.
// ===========================================================================
__global__ __launch_bounds__(512, 1) void rnn1_kernel(
    const f16* __restrict__ h1, f16* __restrict__ h2,
    const float* __restrict__ Wih_f1, const float* __restrict__ Whh_f1, const float* __restrict__ b_f1,
    const float* __restrict__ Wih_b1, const float* __restrict__ Whh_b1, const float* __restrict__ b_b1)
{
    __shared__ float gbuf[8][32][34];
    __shared__ f16  hbuf[256];

    const int tid  = threadIdx.x;
    const int w    = tid >> 6;
    const int lane = tid & 63;
    const int l15  = lane & 15;
    const int quad = lane >> 4;
    const int dir  = blockIdx.x / 100;
    const int blk  = blockIdx.x % 100;
    const int j0   = blk * 8;
    const int jl   = tid >> 5;
    const int bb   = tid & 31;

    const float* Wih = dir ? Wih_b1 : Wih_f1;
    const float* Whh = dir ? Whh_b1 : Whh_f1;
    const float* bs  = dir ? b_b1  : b_f1;

    half8 afr[2][10];
#pragma unroll
    for (int mt = 0; mt < 2; ++mt) {
        const int r = mt * 16 + l15;
        const int grow = (r >> 3) * HH + j0 + (r & 7);
#pragma unroll
        for (int i = 0; i < 10; ++i) {
            const int kt = w + 8 * i;
            half8 v;
#pragma unroll
            for (int jj = 0; jj < 8; ++jj) v[jj] = (f16)0.f;
            if (kt < 75) {
                if (kt < 50) v = cvt8(Wih + (size_t)grow * KROW + kt * 32 + quad * 8);
                else         v = cvt8(Whh + (size_t)grow * HH + (kt - 50) * 32 + quad * 8);
            }
            afr[mt][i] = v;
        }
    }
    const float bi = bs[0 * HH + j0 + jl], bf = bs[1 * HH + j0 + jl],
                bg = bs[2 * HH + j0 + jl], bo = bs[3 * HH + j0 + jl];

    const int KT0 = dir * 25 + (blk >> 2);
    const int q0  = blk & 3;

    // phase-A prefetch registers: up to 7 tiles (kt = w+8i < 50)
    half8 pa[7][2];
    {
        const int t0 = dir ? (TT - 1) : 0;
#pragma unroll
        for (int i = 0; i < 7; ++i) {
            const int kt = w + 8 * i;
            if (kt < 50) {
                const f16* p = h1 + hpi(t0, kt, quad, 0);
                pa[i][0] = *(const half8*)(p + (size_t)l15 * 8);
                pa[i][1] = *(const half8*)(p + (size_t)(16 + l15) * 8);
            }
        }
    }

    float creg = 0.0f;
    for (int s = 0; s < TT; ++s) {
        const int t  = dir ? (TT - 1 - s) : s;
        const int tp = dir ? t + 1 : t - 1;
        const int tn = dir ? (t > 0 ? t - 1 : 0) : (t < TT - 1 ? t + 1 : t);

        // ---- (1) early prefetch of bypass tiles ----
        U64H8 rb[4][2];
        if (s > 0) {
#pragma unroll
            for (int i = 6; i < 10; ++i) {
                const int kt = w + 8 * i;
                if (kt >= 50 && kt < 75) {
                    const f16* p = h2 + hpi(tp, dir * 25 + (kt - 50), quad, 0);
                    rb[i - 6][0].u[0] = ald8(p + (size_t)l15 * 8);
                    rb[i - 6][0].u[1] = ald8(p + (size_t)l15 * 8 + 4);
                    rb[i - 6][1].u[0] = ald8(p + (size_t)(16 + l15) * 8);
                    rb[i - 6][1].u[1] = ald8(p + (size_t)(16 + l15) * 8 + 4);
                }
            }
        }

        floatx4 acc[2][2];
        acc[0][0] = (floatx4)0.f; acc[0][1] = (floatx4)0.f;
        acc[1][0] = (floatx4)0.f; acc[1][1] = (floatx4)0.f;

        // ---- (2) phase A: h1[t] MFMA from prefetched regs ----
#pragma unroll
        for (int i = 0; i < 7; ++i) {
            const int kt = w + 8 * i;
            if (kt < 50) {
                acc[0][0] = __builtin_amdgcn_mfma_f32_16x16x32_f16(afr[0][i], pa[i][0], acc[0][0], 0, 0, 0);
                acc[0][1] = __builtin_amdgcn_mfma_f32_16x16x32_f16(afr[0][i], pa[i][1], acc[0][1], 0, 0, 0);
                acc[1][0] = __builtin_amdgcn_mfma_f32_16x16x32_f16(afr[1][i], pa[i][0], acc[1][0], 0, 0, 0);
                acc[1][1] = __builtin_amdgcn_mfma_f32_16x16x32_f16(afr[1][i], pa[i][1], acc[1][1], 0, 0, 0);
            }
        }

        // ---- (3) reload pa for next step (completes under phase-B wait) ----
#pragma unroll
        for (int i = 0; i < 7; ++i) {
            const int kt = w + 8 * i;
            if (kt < 50) {
                const f16* p = h1 + hpi(tn, kt, quad, 0);
                pa[i][0] = *(const half8*)(p + (size_t)l15 * 8);
                pa[i][1] = *(const half8*)(p + (size_t)(16 + l15) * 8);
            }
        }

        // ---- (4) phase B: bulk verify + bulk respin ----
        if (s > 0) {
            int dm = 0;
#pragma unroll
            for (int i = 6; i < 10; ++i) {
                const int kt = w + 8 * i;
                if (kt >= 50 && kt < 75) {
                    const int bad = (rb[i - 6][0].u[0] == SENT) | (rb[i - 6][0].u[1] == SENT) |
                                    (rb[i - 6][1].u[0] == SENT) | (rb[i - 6][1].u[1] == SENT);
                    dm |= bad << (i - 6);
                }
            }
            while (__any(dm != 0)) {
#pragma unroll
                for (int i = 6; i < 10; ++i) {
                    const int kt = w + 8 * i;
                    if (kt >= 50 && kt < 75) {
                        if (dm & (1 << (i - 6))) {
                            const f16* p = h2 + hpi(tp, dir * 25 + (kt - 50), quad, 0);
                            rb[i - 6][0].u[0] = ald8(p + (size_t)l15 * 8);
                            rb[i - 6][0].u[1] = ald8(p + (size_t)l15 * 8 + 4);
                            rb[i - 6][1].u[0] = ald8(p + (size_t)(16 + l15) * 8);
                            rb[i - 6][1].u[1] = ald8(p + (size_t)(16 + l15) * 8 + 4);
                        }
                    }
                }
                int nm = 0;
#pragma unroll
                for (int i = 6; i < 10; ++i) {
                    const int kt = w + 8 * i;
                    if (kt >= 50 && kt < 75) {
                        if (dm & (1 << (i - 6))) {
                            const int bad = (rb[i - 6][0].u[0] == SENT) | (rb[i - 6][0].u[1] == SENT) |
                                            (rb[i - 6][1].u[0] == SENT) | (rb[i - 6][1].u[1] == SENT);
                            nm |= bad << (i - 6);
                        }
                    }
                }
                dm = nm;
            }
            // ---- phase B MFMA ----
#pragma unroll
            for (int i = 6; i < 10; ++i) {
                const int kt = w + 8 * i;
                if (kt >= 50 && kt < 75) {
                    acc[0][0] = __builtin_amdgcn_mfma_f32_16x16x32_f16(afr[0][i], rb[i - 6][0].h, acc[0][0], 0, 0, 0);
                    acc[0][1] = __builtin_amdgcn_mfma_f32_16x16x32_f16(afr[0][i], rb[i - 6][1].h, acc[0][1], 0, 0, 0);
                    acc[1][0] = __builtin_amdgcn_mfma_f32_16x16x32_f16(afr[1][i], rb[i - 6][0].h, acc[1][0], 0, 0, 0);
                    acc[1][1] = __builtin_amdgcn_mfma_f32_16x16x32_f16(afr[1][i], rb[i - 6][1].h, acc[1][1], 0, 0, 0);
                }
            }
        }

        // ---- (5) cross-wave reduce + epilogue ----
#pragma unroll
        for (int mt = 0; mt < 2; ++mt)
#pragma unroll
            for (int nt = 0; nt < 2; ++nt)
#pragma unroll
                for (int rg = 0; rg < 4; ++rg)
                    gbuf[w][mt * 16 + quad * 4 + rg][nt * 16 + l15] = acc[mt][nt][rg];
        __syncthreads();
        if (tid < 256) {
            float gi_ = bi, gf_ = bf, gc_ = bg, go_ = bo;
#pragma unroll
            for (int ww = 0; ww < 8; ++ww) {
                gi_ += gbuf[ww][jl][bb];
                gf_ += gbuf[ww][8 + jl][bb];
                gc_ += gbuf[ww][16 + jl][bb];
                go_ += gbuf[ww][24 + jl][bb];
            }
            const float cn = sigm(gf_) * creg + sigm(gi_) * ftanh(gc_);
            creg = cn;
            hbuf[bb * 8 + jl] = (f16)(sigm(go_) * ftanh(cn));
        }
        __syncthreads();
        if (tid < BB) {
            f16* dst = h2 + hpi(t, KT0, q0, tid);
            const unsigned long long* src = (const unsigned long long*)(hbuf + tid * 8);
            ast8(dst, src[0]);
            ast8(dst + 4, src[1]);
        }
    }
}

// ---------------------------------------------------------------------------
// prep: xp packed f16, sin/cos tables, sentinel-fill h1+h2 (105 MB)
__global__ void prep_kernel(const float* __restrict__ x, const float* __restrict__ alphabet,
                            f16* __restrict__ xp, float* __restrict__ sin_t,
                            float* __restrict__ cos_t, unsigned* __restrict__ hsent) {
    const int gid = blockIdx.x * blockDim.x + threadIdx.x;
    const int nth = gridDim.x * blockDim.x;
    for (int idx = gid; idx < TT * BB * 64; idx += nth) {
        const int tb = idx >> 6;            // t*32+b
        const int i  = idx & 63;
        const int t  = tb >> 5;
        const int b  = tb & 31;
        const size_t di = ((((size_t)t * 2 + (i >> 5)) * 4 + ((i >> 3) & 3)) * 32 + b) * 8 + (i & 7);
        xp[di] = (i < DIN) ? (f16)x[(size_t)tb * DIN + i] : (f16)0.f;
    }
    uint4v* hs4 = (uint4v*)hsent;
    const uint4v sv = {0xFFFFFFFFu, 0xFFFFFFFFu, 0xFFFFFFFFu, 0xFFFFFFFFu};
    const int n4 = (2 * 13107200) / 4;
    for (int idx = gid; idx < n4; idx += nth) hs4[idx] = sv;
    if (gid < 60) { sin_t[gid] = sinf(alphabet[gid]); cos_t[gid] = cosf(alphabet[gid]); }
}

// logits -> softmax -> dihedral angles (h2 packed [t][KT][q][b][8])
__global__ __launch_bounds__(640, 1) void head_kernel(
    const f16* __restrict__ h2, const float* __restrict__ Wl, const float* __restrict__ bl,
    const float* __restrict__ sin_t, const float* __restrict__ cos_t,
    float* __restrict__ angles) {
    __shared__ float pl[20][33];
    __shared__ float mx[32];
    const int t = blockIdx.x;
    const int a = threadIdx.x / 32;
    const int b = threadIdx.x & 31;
    if (a < 20) {
        float acc = bl[a];
        const float* wr = Wl + (size_t)a * KROW;
        const f16*   hr = h2 + (size_t)t * 50 * 4 * 32 * 8;
        for (int k8 = 0; k8 < KROW / 8; ++k8) {
            const half8 hv = *(const half8*)(hr + (((size_t)k8) * 32 + b) * 8);
            const float4 w0 = *(const float4*)(wr + k8 * 8);
            const float4 w1 = *(const float4*)(wr + k8 * 8 + 4);
            acc = fmaf(w0.x, (float)hv[0], acc);
            acc = fmaf(w0.y, (float)hv[1], acc);
            acc = fmaf(w0.z, (float)hv[2], acc);
            acc = fmaf(w0.w, (float)hv[3], acc);
            acc = fmaf(w1.x, (float)hv[4], acc);
            acc = fmaf(w1.y, (float)hv[5], acc);
            acc = fmaf(w1.z, (float)hv[6], acc);
            acc = fmaf(w1.w, (float)hv[7], acc);
        }
        pl[a][b] = acc;
    }
    __syncthreads();
    if (threadIdx.x < 32) {
        float m = pl[0][threadIdx.x];
        for (int i = 1; i < 20; ++i) m = fmaxf(m, pl[i][threadIdx.x]);
        mx[threadIdx.x] = m;
    }
    __syncthreads();
    if (a < 20) pl[a][b] = __expf(pl[a][b] - mx[b]);
    __syncthreads();
    if (threadIdx.x < 96) {
        const int c = threadIdx.x / 32, b2 = threadIdx.x & 31;
        float y = 0.f, xx = 0.f;
        for (int i = 0; i < 20; ++i) {
            const float e = pl[i][b2];
            y  = fmaf(e, sin_t[i * 3 + c], y);
            xx = fmaf(e, cos_t[i * 3 + c], xx);
        }
        angles[((size_t)t * BB + b2) * 3 + c] = atan2f(y, xx);
    }
}

// sequential NeRF coordinate extension, one lane per batch element.
// angles loads software-prefetched one iteration ahead (latency hiding).
__global__ void coords_kernel(const float* __restrict__ angles, float* __restrict__ out) {
    const int b = threadIdx.x;
    if (b >= BB) return;
    const float rs[3]  = {1.458f, 1.525f, 1.33f};
    const float ths[3] = {2.124f, 1.941f, 2.028f};
    float ct[3], st[3];
#pragma unroll
    for (int k = 0; k < 3; ++k) { ct[k] = cosf(ths[k]); st[k] = sinf(ths[k]); }
    float pax = 0.f,     pay = 0.f, paz = 0.f;
    float pbx = 1.458f,  pby = 0.f, pbz = 0.f;
    float pcx = 2.f,     pcy = 1.f, pcz = 0.f;
    float phi_next = angles[(size_t)b * 3];
    for (int n = 0; n < 3 * TT; ++n) {
        const float phi = phi_next;
        if (n + 1 < 3 * TT) {
            const int t2 = (n + 1) / 3;
            const int k2 = (n + 1) - 3 * t2;
            phi_next = angles[(size_t)t2 * 96 + b * 3 + k2];
        }
        float ux = pcx - pbx, uy = pcy - pby, uz = pcz - pbz;
        const float il = rsqrtf(ux * ux + uy * uy + uz * uz);
        const float bcx = ux * il, bcy = uy * il, bcz = uz * il;
        const float wx = pbx - pax, wy = pby - pay, wz = pbz - paz;
        float cx = wy * bcz - wz * bcy, cy = wz * bcx - wx * bcz, cz = wx * bcy - wy * bcx;
        const float iln = rsqrtf(cx * cx + cy * cy + cz * cz);
        const float nx = cx * iln, ny = cy * iln, nz = cz * iln;
        const float mxv = ny * bcz - nz * bcy, myv = nz * bcx - nx * bcz, mzv = nx * bcy - ny * bcx;
        float sp, cp;
        __sincosf(phi, &sp, &cp);
        const int k = n - 3 * (n / 3);
        const float rr = rs[k], cth = ct[k], sth = st[k];
        const float dx = pcx - rr * cth * bcx + rr * sth * (cp * mxv + sp * nx);
        const float dy = pcy - rr * cth * bcy + rr * sth * (cp * myv + sp * ny);
        const float dz = pcz - rr * cth * bcz + rr * sth * (cp * mzv + sp * nz);
        float* o = out + ((size_t)n * BB + b) * 3;
        o[0] = dx; o[1] = dy; o[2] = dz;
        pax = pbx; pay = pby; paz = pbz;
        pbx = pcx; pby = pcy; pbz = pcz;
        pcx = dx;  pcy = dy;  pcz = dz;
    }
}

// ---------------------------------------------------------------------------
extern "C" void kernel_launch(void* const* d_in, const int* in_sizes, int n_in,
                              void* d_out, int out_size, void* d_ws, size_t ws_size,
                              hipStream_t stream) {
    (void)in_sizes; (void)n_in; (void)out_size; (void)ws_size;
    const float* x      = (const float*)d_in[0];
    const float* Wih_f0 = (const float*)d_in[1];
    const float* Whh_f0 = (const float*)d_in[2];
    const float* b_f0   = (const float*)d_in[3];
    const float* Wih_b0 = (const float*)d_in[4];
    const float* Whh_b0 = (const float*)d_in[5];
    const float* b_b0   = (const float*)d_in[6];
    const float* Wih_f1 = (const float*)d_in[7];
    const float* Whh_f1 = (const float*)d_in[8];
    const float* b_f1   = (const float*)d_in[9];
    const float* Wih_b1 = (const float*)d_in[10];
    const float* Whh_b1 = (const float*)d_in[11];
    const float* b_b1   = (const float*)d_in[12];
    const float* Wl     = (const float*)d_in[13];
    const float* bl     = (const float*)d_in[14];
    const float* alphabet = (const float*)d_in[15];

    float* ws = (float*)d_ws;
    f16*   xp     = (f16*)(ws + OFF_XT);
    f16*   h1     = (f16*)(ws + OFF_H1);
    f16*   h2     = (f16*)(ws + OFF_H2);
    float* angles = ws + OFF_ANG;
    float* sin_t  = ws + OFF_SIN;
    float* cos_t  = ws + OFF_COS;

    prep_kernel<<<1024, 256, 0, stream>>>(x, alphabet, xp, sin_t, cos_t, (unsigned*)(ws + OFF_H1));
    rnn0_kernel<<<200, 512, 0, stream>>>(xp, h1,
        Wih_f0, Whh_f0, b_f0, Wih_b0, Whh_b0, b_b0);
    rnn1_kernel<<<200, 512, 0, stream>>>(h1, h2,
        Wih_f1, Whh_f1, b_f1, Wih_b1, Whh_b1, b_b1);
    head_kernel<<<TT, 640, 0, stream>>>(h2, Wl, bl, sin_t, cos_t, angles);
    coords_kernel<<<1, 64, 0, stream>>>(angles, (float*)d_out);
}